// Round 4
// baseline (376.209 us; speedup 1.0000x reference)
//
#include <hip/hip_runtime.h>
#include <float.h>

typedef __attribute__((ext_vector_type(8))) short short8;   // 8 bf16 (4 VGPRs)
typedef __attribute__((ext_vector_type(4))) float f32x4;    // MFMA C/D

// ---------------- workspace layout (float offsets) ----------------
static constexpr size_t OFF_H1    = 0;          // 8*256*1024 = 2,097,152 (dead after h2; reused for h2T)
static constexpr size_t OFF_H2    = 2097152;    // 8*64*2048  = 1,048,576
static constexpr size_t OFF_FEAT  = 3145728;    // knn partials, then feat2a/2b, then h4 = 4,194,304
static constexpr size_t OFF_FINAL = 7340032;    // 8*192*2048 = 3,145,728
static constexpr size_t OFF_Y     = 10485760;   // 1,048,576
static constexpr size_t OFF_Z     = 11534336;   // 1,048,576
static constexpr size_t OFF_XX    = 12582912;   // 8*2048 = 16,384
static constexpr size_t OFF_G     = 12599296;   // 8*64 = 512
static constexpr size_t OFF_G3B   = 12599808;   // 8*128 = 1024
static constexpr size_t OFF_IDX   = 12600832;   // 8*2048*4 ints = 65,536
static constexpr size_t WS_FLOATS = 12666368;   // ~48.3 MB
static constexpr size_t OFF_THI   = OFF_H1;               // bf16 hi, [b][2048][64]
static constexpr size_t OFF_TLO   = OFF_H1 + 524288;      // bf16 lo
static constexpr size_t OFF_PART  = OFF_FEAT;             // knn partial top-4: 8*4*2048*8 floats = 2 MB

// async 16B global->LDS. LDS dest = wave-uniform base + lane*16
__device__ __forceinline__ void gl_lds16(const void* g, void* l) {
    __builtin_amdgcn_global_load_lds(
        (const __attribute__((address_space(1))) void*)g,
        (__attribute__((address_space(3))) void*)l, 16, 0, 0);
}

// bf16 round-to-nearest-even
__device__ __forceinline__ unsigned short f2bf(float x) {
    union { float f; unsigned int u; } v; v.f = x;
    unsigned int r = v.u + 0x7fffu + ((v.u >> 16) & 1u);
    return (unsigned short)(r >> 16);
}
__device__ __forceinline__ float bf2f(unsigned short h) {
    union { unsigned int u; float f; } v; v.u = ((unsigned int)h) << 16;
    return v.f;
}
__device__ __forceinline__ void split2(float x, unsigned short& h, unsigned short& l) {
    h = f2bf(x);
    l = f2bf(x - bf2f(h));
}

// ---- top-4 insertion, (value desc, index asc); equal value keeps lower index ----
static __device__ __forceinline__ void ins4(float v, int m, float bv[4], int bi[4])
{
#pragma unroll
    for (int s = 0; s < 4; ++s) {
        bool better = (v > bv[s]) || (v == bv[s] && m < bi[s]);
        float tv = bv[s]; int tm = bi[s];
        bv[s] = better ? v : bv[s];
        bi[s] = better ? m : bi[s];
        v = better ? tv : v;
        m = better ? tm : m;
    }
}

// =================================================================
// Transpose + bf16-split h2: fp32 [b][64][2048] -> thi/tlo [b][2048][64]
// =================================================================
__global__ __launch_bounds__(256) void tsplit_h2(const float* __restrict__ h2,
                                                 unsigned short* __restrict__ thi,
                                                 unsigned short* __restrict__ tlo)
{
    const int b  = blockIdx.y;
    const int n0 = blockIdx.x * 64;
    const int t  = threadIdx.x;
    __shared__ float tile[64][65];
    const float* hb = h2 + (size_t)b * 64 * 2048;
#pragma unroll
    for (int i = 0; i < 16; ++i) {
        int c = i * 4 + (t >> 6), n = t & 63;
        tile[c][n] = hb[(size_t)c * 2048 + n0 + n];
    }
    __syncthreads();
    unsigned short* th = thi + (size_t)b * 2048 * 64;
    unsigned short* tl = tlo + (size_t)b * 2048 * 64;
#pragma unroll
    for (int i = 0; i < 16; ++i) {
        int n = i * 4 + (t >> 6), c = t & 63;
        unsigned short h, l;
        split2(tile[c][n], h, l);
        th[(size_t)(n0 + n) * 64 + c] = h;
        tl[(size_t)(n0 + n) * 64 + c] = l;
    }
}

// =================================================================
// Fused pairwise-distance + top-4 kNN, split-bf16 MFMA, LDS-shared B.
// Score = fma(2, dot, -xx[m])  (xx[n] dropped: constant per row -> ranking
// within a row, and hence top-4 indices, unchanged).
// Block: 4 waves x 32 rows = 128 rows; sweeps an m-quarter (512 m, 8 tiles).
// B-tile staged chunk-major (slot = chunk*64 + m) via global_load_lds:
// ds_read_b128 b-frags are bank-conflict-free (bank=4*j, 2-way only).
// Double-buffered (m97 pattern). Per-row top-4 in regs; shfl_xor butterfly
// merge across the 16 j-lanes; partial lists to global; knn_merge combines.
// =================================================================
struct __align__(16) KBuf {
    unsigned short hi[4096];   // 8 chunks x 64 m x 8 bf16
    unsigned short lo[4096];
    float xm[64];
};

__global__ __launch_bounds__(256) void knn_mfma2(const unsigned short* __restrict__ thi,
                                                 const unsigned short* __restrict__ tlo,
                                                 const float* __restrict__ xx,
                                                 float* __restrict__ part)
{
    const int b    = blockIdx.z;
    const int mq   = blockIdx.y;            // m-quarter
    const int t    = threadIdx.x;
    const int wu   = __builtin_amdgcn_readfirstlane(t >> 6);
    const int lane = t & 63;
    const int j    = lane & 15;
    const int q    = lane >> 4;
    const int nrow0 = blockIdx.x * 128 + wu * 32;   // wave's 32-row base

    const unsigned short* th = thi + (size_t)b * 2048 * 64;
    const unsigned short* tl = tlo + (size_t)b * 2048 * 64;
    const float* xb = xx + (size_t)b * 2048;

    __shared__ KBuf sb[2];

    // A fragments: 2 row-tiles x 2 k-steps x {hi,lo}
    short8 ah[2][2], al[2][2];
#pragma unroll
    for (int rt = 0; rt < 2; ++rt) {
        const size_t row = (size_t)(nrow0 + rt * 16 + j) * 64;
        ah[rt][0] = *(const short8*)(th + row + q * 8);
        ah[rt][1] = *(const short8*)(th + row + 32 + q * 8);
        al[rt][0] = *(const short8*)(tl + row + q * 8);
        al[rt][1] = *(const short8*)(tl + row + 32 + q * 8);
    }

    float bv[8][4]; int bi[8][4];   // [rt*4+r][slot]
#pragma unroll
    for (int r = 0; r < 8; ++r)
#pragma unroll
        for (int s = 0; s < 4; ++s) { bv[r][s] = -FLT_MAX; bi[r][s] = 0x7fffffff; }

    const int mbeg = mq * 512;

    // ---- staging lambda-equivalent (macro'd inline) ----
#define KNN_STAGE(BUF, M0)                                                        \
    {                                                                             \
        const unsigned short* sh = th + (size_t)((M0) + lane) * 64;               \
        const unsigned short* sl = tl + (size_t)((M0) + lane) * 64;               \
        gl_lds16(sh + (2 * wu) * 8,     &sb[BUF].hi[(2 * wu) * 512]);             \
        gl_lds16(sh + (2 * wu + 1) * 8, &sb[BUF].hi[(2 * wu + 1) * 512]);         \
        gl_lds16(sl + (2 * wu) * 8,     &sb[BUF].lo[(2 * wu) * 512]);             \
        gl_lds16(sl + (2 * wu + 1) * 8, &sb[BUF].lo[(2 * wu + 1) * 512]);         \
        if (wu == 0 && lane < 16) gl_lds16(xb + (M0) + lane * 4, &sb[BUF].xm[0]); \
    }

    KNN_STAGE(0, mbeg)

    for (int tt = 0; tt < 8; ++tt) {
        __syncthreads();                    // drains vmcnt -> current buffer ready
        if (tt < 7) KNN_STAGE((tt + 1) & 1, mbeg + (tt + 1) * 64)
        const KBuf& bf = sb[tt & 1];
        const int m0 = mbeg + tt * 64;

#pragma unroll
        for (int sub = 0; sub < 4; ++sub) {
            const int ml = sub * 16 + j;
            short8 bh0 = *(const short8*)&bf.hi[(q) * 512 + ml * 8];
            short8 bh1 = *(const short8*)&bf.hi[(4 + q) * 512 + ml * 8];
            short8 bl0 = *(const short8*)&bf.lo[(q) * 512 + ml * 8];
            short8 bl1 = *(const short8*)&bf.lo[(4 + q) * 512 + ml * 8];
            const float xmv = bf.xm[ml];
            const int mcol = m0 + ml;

#pragma unroll
            for (int rt = 0; rt < 2; ++rt) {
                f32x4 acc = (f32x4){0.f, 0.f, 0.f, 0.f};
                acc = __builtin_amdgcn_mfma_f32_16x16x32_bf16(ah[rt][0], bh0, acc, 0, 0, 0);
                acc = __builtin_amdgcn_mfma_f32_16x16x32_bf16(ah[rt][0], bl0, acc, 0, 0, 0);
                acc = __builtin_amdgcn_mfma_f32_16x16x32_bf16(al[rt][0], bh0, acc, 0, 0, 0);
                acc = __builtin_amdgcn_mfma_f32_16x16x32_bf16(al[rt][0], bl0, acc, 0, 0, 0);
                acc = __builtin_amdgcn_mfma_f32_16x16x32_bf16(ah[rt][1], bh1, acc, 0, 0, 0);
                acc = __builtin_amdgcn_mfma_f32_16x16x32_bf16(ah[rt][1], bl1, acc, 0, 0, 0);
                acc = __builtin_amdgcn_mfma_f32_16x16x32_bf16(al[rt][1], bh1, acc, 0, 0, 0);
                acc = __builtin_amdgcn_mfma_f32_16x16x32_bf16(al[rt][1], bl1, acc, 0, 0, 0);

                float pdv[4];
#pragma unroll
                for (int r = 0; r < 4; ++r)
                    pdv[r] = __builtin_fmaf(2.f, acc[r], -xmv);

#pragma unroll
                for (int r = 0; r < 4; ++r) {
                    float* lv = bv[rt * 4 + r];
                    int*   li = bi[rt * 4 + r];
                    if (pdv[r] >= lv[3]) ins4(pdv[r], mcol, lv, li);
                }
            }
        }
    }

    // ---- in-wave butterfly merge across the 16 j-lanes of each row ----
#pragma unroll
    for (int rr = 0; rr < 8; ++rr) {
#pragma unroll
        for (int mask = 1; mask < 16; mask <<= 1) {
            float pv[4]; int pi[4];
#pragma unroll
            for (int s = 0; s < 4; ++s) {
                pv[s] = __shfl_xor(bv[rr][s], mask, 64);
                pi[s] = __shfl_xor(bi[rr][s], mask, 64);
            }
#pragma unroll
            for (int s = 0; s < 4; ++s) ins4(pv[s], pi[s], bv[rr], bi[rr]);
        }
    }
    if (j == 0) {
#pragma unroll
        for (int rt = 0; rt < 2; ++rt)
#pragma unroll
            for (int r = 0; r < 4; ++r) {
                const int nrow = nrow0 + rt * 16 + q * 4 + r;
                const size_t off = (((size_t)b * 4 + mq) * 2048 + nrow) * 8;
                float4 vv; int4 ii;
                vv.x = bv[rt * 4 + r][0]; vv.y = bv[rt * 4 + r][1];
                vv.z = bv[rt * 4 + r][2]; vv.w = bv[rt * 4 + r][3];
                ii.x = bi[rt * 4 + r][0]; ii.y = bi[rt * 4 + r][1];
                ii.z = bi[rt * 4 + r][2]; ii.w = bi[rt * 4 + r][3];
                *(float4*)(part + off) = vv;
                *(int4*)(part + off + 4) = ii;
            }
    }
#undef KNN_STAGE
}

// combine the 4 m-quarter partial lists -> final top-4 indices
__global__ __launch_bounds__(256) void knn_merge(const float* __restrict__ part,
                                                 int* __restrict__ idxout)
{
    int t = blockIdx.x * 256 + threadIdx.x;   // 16384
    int b = t >> 11, n = t & 2047;
    float fv[4]; int fi[4];
#pragma unroll
    for (int s = 0; s < 4; ++s) { fv[s] = -FLT_MAX; fi[s] = 0x7fffffff; }
    for (int qt = 0; qt < 4; ++qt) {
        const float* p = part + (((size_t)b * 4 + qt) * 2048 + n) * 8;
        float4 pv = *(const float4*)p;
        int4   pi = *(const int4*)(p + 4);
        ins4(pv.x, pi.x, fv, fi);
        ins4(pv.y, pi.y, fv, fi);
        ins4(pv.z, pi.z, fv, fi);
        ins4(pv.w, pi.w, fv, fi);
    }
    int4 o4; o4.x = fi[0]; o4.y = fi[1]; o4.z = fi[2]; o4.w = fi[3];
    *(int4*)(idxout + ((size_t)b * 2048 + n) * 4) = o4;
}

// =================================================================
// Scalar-weight conv GEMM (unchanged from round 2)
// =================================================================
template<int C, int OW, bool MAXK, bool RELU>
__global__ __launch_bounds__(256, 2) void conv_sw(
    const float* __restrict__ W, int wstride,
    const float* __restrict__ scale, const float* __restrict__ bias,
    const float* __restrict__ in, size_t ibstride, int irstride,
    float* __restrict__ out, size_t obstride, int orstride)
{
    const int t    = threadIdx.x;
    const int wu   = __builtin_amdgcn_readfirstlane(t >> 6);
    const int lane = t & 63;
    const int n0   = blockIdx.x * 256;
    const int ob   = blockIdx.y * (OW * 4) + wu * OW;
    const int b    = blockIdx.z;
    const float* inb = in + (size_t)b * ibstride;
    float* outb = out + (size_t)b * obstride;

    __shared__ float lt[64][256];

    float acc[OW][4];
#pragma unroll
    for (int r = 0; r < OW; ++r)
#pragma unroll
        for (int jj = 0; jj < 4; ++jj) acc[r][jj] = 0.f;

    for (int c0 = 0; c0 < C; c0 += 64) {
        __syncthreads();
#pragma unroll
        for (int i = 0; i < 16; ++i) {
            const int c = i * 4 + wu;
            gl_lds16(inb + (size_t)(c0 + c) * irstride + n0 + lane * 4, &lt[c][0]);
        }
        __syncthreads();

#pragma unroll 4
        for (int c = 0; c < 64; ++c) {
            float4 mv = *(const float4*)&lt[c][lane * 4];
#pragma unroll
            for (int r = 0; r < OW; ++r) {
                const float wv = W[(size_t)(ob + r) * wstride + c0 + c];
                acc[r][0] += wv * mv.x;
                acc[r][1] += wv * mv.y;
                acc[r][2] += wv * mv.z;
                acc[r][3] += wv * mv.w;
            }
        }
    }

#pragma unroll
    for (int r = 0; r < OW; ++r) {
        const int o = ob + r;
        const float s  = scale ? scale[o] : 1.0f;
        const float bb = bias  ? bias[o]  : 0.0f;
        if constexpr (MAXK) {
            float v = -FLT_MAX;
#pragma unroll
            for (int jj = 0; jj < 4; ++jj)
                v = fmaxf(v, fmaxf(acc[r][jj] * s + bb, 0.f));
            outb[(size_t)o * orstride + (n0 >> 2) + lane] = v;
        } else {
            float4 rr;
            rr.x = acc[r][0] * s + bb;
            rr.y = acc[r][1] * s + bb;
            rr.z = acc[r][2] * s + bb;
            rr.w = acc[r][3] * s + bb;
            if constexpr (RELU) {
                rr.x = fmaxf(rr.x, 0.f); rr.y = fmaxf(rr.y, 0.f);
                rr.z = fmaxf(rr.z, 0.f); rr.w = fmaxf(rr.w, 0.f);
            }
            *(float4*)(outb + (size_t)o * orstride + n0 + lane * 4) = rr;
        }
    }
}

// xx[b,n] = sum_c h2[b,c,n]^2
__global__ __launch_bounds__(256) void xx_kernel(const float* __restrict__ h2, float* __restrict__ xx)
{
    int t = blockIdx.x * 256 + threadIdx.x;
    int n = t & 2047, b = t >> 11;
    const float* hb = h2 + (size_t)b * 64 * 2048 + n;
    float a = 0.f;
#pragma unroll
    for (int c = 0; c < 64; ++c) { float v = hb[(size_t)c * 2048]; a += v * v; }
    xx[t] = a;
}

// g[b,c] = max_n h2[b,c,n]
__global__ __launch_bounds__(256) void gmax_kernel(const float* __restrict__ h2, float* __restrict__ g)
{
    const int c = blockIdx.x;
    const int b = blockIdx.y;
    const float* hb = h2 + ((size_t)b * 64 + c) * 2048;
    float m = -FLT_MAX;
    for (int n = threadIdx.x; n < 2048; n += 256) m = fmaxf(m, hb[n]);
#pragma unroll
    for (int off = 32; off > 0; off >>= 1) m = fmaxf(m, __shfl_down(m, off, 64));
    __shared__ float sm[4];
    if ((threadIdx.x & 63) == 0) sm[threadIdx.x >> 6] = m;
    __syncthreads();
    if (threadIdx.x == 0)
        g[(size_t)b * 64 + c] = fmaxf(fmaxf(sm[0], sm[1]), fmaxf(sm[2], sm[3]));
}

// feat2a[b,o,n,k] = relu((y[b,o,idx[b,n,k]] - y[b,o,n] + z[b,o,n])*s2a[o] + b2a[o])
__global__ __launch_bounds__(256) void feat2a_kernel(
    const float* __restrict__ y, const float* __restrict__ z, const int* __restrict__ idx,
    const float* __restrict__ s2a, const float* __restrict__ b2a, float* __restrict__ out)
{
    int t = blockIdx.x * 256 + threadIdx.x;
    int n = t & 2047, o = (t >> 11) & 63, b = t >> 17;
    const float* yb = y + (size_t)(b * 64 + o) * 2048;
    const float* zb = z + (size_t)(b * 64 + o) * 2048;
    int4 id = *(const int4*)(idx + ((size_t)b * 2048 + n) * 4);
    float yn = yb[n], zn = zb[n];
    float base = zn - yn;
    float s = s2a[o], bb = b2a[o];
    float4 r;
    r.x = fmaxf((yb[id.x] + base) * s + bb, 0.f);
    r.y = fmaxf((yb[id.y] + base) * s + bb, 0.f);
    r.z = fmaxf((yb[id.z] + base) * s + bb, 0.f);
    r.w = fmaxf((yb[id.w] + base) * s + bb, 0.f);
    *(float4*)(out + ((size_t)(b * 64 + o) * 2048 + n) * 4) = r;
}

// g3b[b,:] = relu((W3b @ relu((W3a @ g)*s3a+b3a))*s3b+b3b)
__global__ __launch_bounds__(128) void gconv_kernel(
    const float* __restrict__ g,
    const float* __restrict__ W3a, const float* __restrict__ s3a, const float* __restrict__ b3a,
    const float* __restrict__ W3b, const float* __restrict__ s3b, const float* __restrict__ b3b,
    float* __restrict__ g3b)
{
    const int b = blockIdx.x;
    const int t = threadIdx.x;
    __shared__ float gl[64], ga[128];
    if (t < 64) gl[t] = g[(size_t)b * 64 + t];
    __syncthreads();
    float a = 0.f;
#pragma unroll
    for (int c = 0; c < 64; ++c) a += W3a[t * 64 + c] * gl[c];
    ga[t] = fmaxf(a * s3a[t] + b3a[t], 0.f);
    __syncthreads();
    float o = 0.f;
#pragma unroll
    for (int c = 0; c < 128; ++c) o += W3b[t * 128 + c] * ga[c];
    g3b[(size_t)b * 128 + t] = fmaxf(o * s3b[t] + b3b[t], 0.f);
}

// final[b, 64+j, n] = g3b[b, j]
__global__ __launch_bounds__(256) void bcast_kernel(const float* __restrict__ g3b, float* __restrict__ fin)
{
    int t = blockIdx.x * 256 + threadIdx.x;
    int n = t & 2047, jj = (t >> 11) & 127, b = t >> 18;
    fin[((size_t)b * 192 + 64 + jj) * 2048 + n] = g3b[(size_t)b * 128 + jj];
}

// out[b,o,n] = sum_c W4b[o,c]*h4[b,c,n] + b4b[o], o<3
__global__ __launch_bounds__(256) void conv4b_kernel(const float* __restrict__ h4,
    const float* __restrict__ W, const float* __restrict__ bias, float* __restrict__ out)
{
    __shared__ float Wl[768];
    for (int i = threadIdx.x; i < 768; i += 256) Wl[i] = W[i];
    __syncthreads();
    int t = blockIdx.x * 256 + threadIdx.x;
    int n = t & 2047, b = t >> 11;
    const float* hb = h4 + (size_t)b * 256 * 2048 + n;
    float a0 = 0.f, a1 = 0.f, a2 = 0.f;
#pragma unroll 8
    for (int c = 0; c < 256; ++c) {
        float v = hb[(size_t)c * 2048];
        a0 += Wl[c] * v;
        a1 += Wl[256 + c] * v;
        a2 += Wl[512 + c] * v;
    }
    float* ob = out + (size_t)b * 3 * 2048 + n;
    ob[0]    = a0 + bias[0];
    ob[2048] = a1 + bias[1];
    ob[4096] = a2 + bias[2];
}

extern "C" void kernel_launch(void* const* d_in, const int* in_sizes, int n_in,
                              void* d_out, int out_size, void* d_ws, size_t ws_size,
                              hipStream_t stream)
{
    const float* x     = (const float*)d_in[0];
    const float* W_dup = (const float*)d_in[1];
    const float* s_dup = (const float*)d_in[2];
    const float* b_dup = (const float*)d_in[3];
    const float* W_c1  = (const float*)d_in[4];
    const float* s_c1  = (const float*)d_in[5];
    const float* b_c1  = (const float*)d_in[6];
    const float* W2a   = (const float*)d_in[7];
    const float* s2a   = (const float*)d_in[8];
    const float* b2a   = (const float*)d_in[9];
    const float* W2b   = (const float*)d_in[10];
    const float* s2b   = (const float*)d_in[11];
    const float* b2b   = (const float*)d_in[12];
    const float* W2c   = (const float*)d_in[13];
    const float* s2c   = (const float*)d_in[14];
    const float* b2c   = (const float*)d_in[15];
    const float* W3a   = (const float*)d_in[16];
    const float* s3a   = (const float*)d_in[17];
    const float* b3a   = (const float*)d_in[18];
    const float* W3b   = (const float*)d_in[19];
    const float* s3b   = (const float*)d_in[20];
    const float* b3b   = (const float*)d_in[21];
    const float* W4a   = (const float*)d_in[22];
    const float* b4a   = (const float*)d_in[23];
    const float* W4b   = (const float*)d_in[24];
    const float* b4b   = (const float*)d_in[25];

    if (ws_size < WS_FLOATS * sizeof(float)) return;

    float* ws   = (float*)d_ws;
    float* h1   = ws + OFF_H1;
    float* h2   = ws + OFF_H2;
    float* feat = ws + OFF_FEAT;
    float* fin  = ws + OFF_FINAL;
    float* y    = ws + OFF_Y;
    float* z    = ws + OFF_Z;
    float* xxb  = ws + OFF_XX;
    float* g    = ws + OFF_G;
    float* g3b  = ws + OFF_G3B;
    int*   idx  = (int*)(ws + OFF_IDX);
    float* part = ws + OFF_PART;   // aliases feat region (dead until feat2a)
    unsigned short* thi = (unsigned short*)(ws + OFF_THI);
    unsigned short* tlo = (unsigned short*)(ws + OFF_TLO);
    float* out  = (float*)d_out;

    // 1) h1 = relu((W_dup @ x)*s+b)  (B,256,1024)
    conv_sw<128, 8, false, true><<<dim3(4, 8, 8), 256, 0, stream>>>(
        W_dup, 128, s_dup, b_dup, x, (size_t)128 * 1024, 1024, h1, (size_t)256 * 1024, 1024);
    // 2) h2 = relu((W_c1 @ h1r)*s+b) (B,64,2048)
    conv_sw<128, 8, false, true><<<dim3(8, 2, 8), 256, 0, stream>>>(
        W_c1, 128, s_c1, b_c1, h1, (size_t)128 * 2048, 2048, h2, (size_t)64 * 2048, 2048);
    // 3) xx + per-channel max + transpose-split h2
    xx_kernel<<<64, 256, 0, stream>>>(h2, xxb);
    gmax_kernel<<<dim3(64, 8), 256, 0, stream>>>(h2, g);
    tsplit_h2<<<dim3(32, 8), 256, 0, stream>>>(h2, thi, tlo);
    // 4) kNN: partial top-4 per m-quarter, then merge
    knn_mfma2<<<dim3(16, 4, 8), 256, 0, stream>>>(thi, tlo, xxb, part);
    knn_merge<<<64, 256, 0, stream>>>(part, idx);
    // 5) y = W2a[:, :64] @ h2 ; z = W2a[:, 64:] @ h2
    conv_sw<64, 8, false, false><<<dim3(8, 2, 8), 256, 0, stream>>>(
        W2a, 128, nullptr, nullptr, h2, (size_t)64 * 2048, 2048, y, (size_t)64 * 2048, 2048);
    conv_sw<64, 8, false, false><<<dim3(8, 2, 8), 256, 0, stream>>>(
        W2a + 64, 128, nullptr, nullptr, h2, (size_t)64 * 2048, 2048, z, (size_t)64 * 2048, 2048);
    // 6) conv2a via gather -> feat (B,64,2048,4)  (part region now dead)
    feat2a_kernel<<<4096, 256, 0, stream>>>(y, z, idx, s2a, b2a, feat);
    // 7) conv2b in-place
    conv_sw<64, 16, false, true><<<dim3(32, 1, 8), 256, 0, stream>>>(
        W2b, 64, s2b, b2b, feat, (size_t)64 * 8192, 8192, feat, (size_t)64 * 8192, 8192);
    // 8) conv2c + max over k -> final channels 0..63
    conv_sw<64, 8, true, true><<<dim3(32, 2, 8), 256, 0, stream>>>(
        W2c, 64, s2c, b2c, feat, (size_t)64 * 8192, 8192, fin, (size_t)192 * 2048, 2048);
    // 9) tiny g-convs
    gconv_kernel<<<8, 128, 0, stream>>>(g, W3a, s3a, b3a, W3b, s3b, b3b, g3b);
    // 10) broadcast g3b into final channels 64..191
    bcast_kernel<<<8192, 256, 0, stream>>>(g3b, fin);
    // 11) h4 = relu(W4a @ final + b4a) -> feat region
    conv_sw<192, 8, false, true><<<dim3(8, 8, 8), 256, 0, stream>>>(
        W4a, 192, nullptr, b4a, fin, (size_t)192 * 2048, 2048, feat, (size_t)256 * 2048, 2048);
    // 12) out = W4b @ h4 + b4b  (B,3,2048)
    conv4b_kernel<<<64, 256, 0, stream>>>(feat, W4b, b4b, out);
}